// Round 4
// baseline (304.721 us; speedup 1.0000x reference)
//
#include <hip/hip_runtime.h>
#include <hip/hip_bf16.h>

#define B_ 4
#define S_ 2048
#define E_ 1024
#define H_ 8
#define D_ 128

using f16x8 = __attribute__((ext_vector_type(8))) _Float16;
using f32x4 = __attribute__((ext_vector_type(4))) float;

__device__ __forceinline__ ushort f2h_bits(float f) {
    union { _Float16 h; ushort u; } cv; cv.h = (_Float16)f; return cv.u;
}
__device__ __forceinline__ f16x8 pack8(const float* __restrict__ p) {
    float4 f0 = *(const float4*)p;
    float4 f1 = *(const float4*)(p + 4);
    f16x8 r;
    r[0] = (_Float16)f0.x; r[1] = (_Float16)f0.y;
    r[2] = (_Float16)f0.z; r[3] = (_Float16)f0.w;
    r[4] = (_Float16)f1.x; r[5] = (_Float16)f1.y;
    r[6] = (_Float16)f1.z; r[7] = (_Float16)f1.w;
    return r;
}

// direct global->LDS DMA, 16B per lane; LDS dest is wave-uniform base + lane*16
__device__ __forceinline__ void gll16(const ushort* g, ushort* l) {
    __builtin_amdgcn_global_load_lds(
        (const __attribute__((address_space(1))) unsigned int*)g,
        (__attribute__((address_space(3))) unsigned int*)l, 16, 0, 0);
}

// ---------------- K/V projection (R2 version — fastest measured) ----------------
// grid: (B*S/128, H), block 256.
// K out: [B,H,S,D] fp16, pre-swizzled: within each s-row, 8-elem chunk at
//   position p holds logical chunk p ^ (s&7).
// V out TRANSPOSED [B,H,D,S] fp16, pre-swizzled (64-block-local, 3-bit XOR):
//   position p holds logical chunk p ^ (d&7).
__global__ __launch_bounds__(256) void kv_proj(
    const float* __restrict__ seq,
    const float* __restrict__ Wk, const float* __restrict__ Wv,
    const float* __restrict__ bk, const float* __restrict__ bv,
    ushort* __restrict__ ko, ushort* __restrict__ vo)
{
    constexpr int TS = 136;
    __shared__ ushort Tk[128 * TS];   // [s_local][d]  (swizzled cols)
    __shared__ ushort Tv[128 * TS];   // [d][s_local]
    const int m0 = blockIdx.x * 128, h = blockIdx.y;
    const int tid = threadIdx.x, lane = tid & 63, w = tid >> 6;
    const int l16 = lane & 15, quad = lane >> 4;

    // A-frags: A[m=lane&15][k=quad*8+j]
    f16x8 a[2][4];
    #pragma unroll
    for (int mt = 0; mt < 2; ++mt)
        #pragma unroll
        for (int ks = 0; ks < 4; ++ks)
            a[mt][ks] = pack8(&seq[(size_t)(m0 + w * 32 + mt * 16 + l16) * E_
                                   + h * D_ + ks * 32 + quad * 8]);

    // ---- K ----
    {
        const float* W = Wk + (size_t)h * D_ * D_;
        f32x4 acc[2][8];
        #pragma unroll
        for (int mt = 0; mt < 2; ++mt)
            #pragma unroll
            for (int nt = 0; nt < 8; ++nt) { f32x4 z = {0.f,0.f,0.f,0.f}; acc[mt][nt] = z; }
        #pragma unroll
        for (int ks = 0; ks < 4; ++ks)
            #pragma unroll
            for (int nt = 0; nt < 8; ++nt) {
                f16x8 bfr = pack8(&W[(size_t)(nt * 16 + l16) * D_ + ks * 32 + quad * 8]);
                #pragma unroll
                for (int mt = 0; mt < 2; ++mt)
                    acc[mt][nt] = __builtin_amdgcn_mfma_f32_16x16x32_f16(
                        a[mt][ks], bfr, acc[mt][nt], 0, 0, 0);
            }
        #pragma unroll
        for (int nt = 0; nt < 8; ++nt) {
            int o = nt * 16 + l16;
            float bias = bk[h * D_ + o];
            #pragma unroll
            for (int mt = 0; mt < 2; ++mt)
                #pragma unroll
                for (int r = 0; r < 4; ++r) {
                    int row = w * 32 + mt * 16 + quad * 4 + r;
                    Tk[row * TS + (o ^ (quad << 3))] = f2h_bits(acc[mt][nt][r] + bias);
                }
        }
    }
    // ---- V ----
    {
        const float* W = Wv + (size_t)h * D_ * D_;
        f32x4 acc[2][8];
        #pragma unroll
        for (int mt = 0; mt < 2; ++mt)
            #pragma unroll
            for (int nt = 0; nt < 8; ++nt) { f32x4 z = {0.f,0.f,0.f,0.f}; acc[mt][nt] = z; }
        #pragma unroll
        for (int ks = 0; ks < 4; ++ks)
            #pragma unroll
            for (int nt = 0; nt < 8; ++nt) {
                f16x8 bfr = pack8(&W[(size_t)(nt * 16 + l16) * D_ + ks * 32 + quad * 8]);
                #pragma unroll
                for (int mt = 0; mt < 2; ++mt)
                    acc[mt][nt] = __builtin_amdgcn_mfma_f32_16x16x32_f16(
                        a[mt][ks], bfr, acc[mt][nt], 0, 0, 0);
            }
        #pragma unroll
        for (int nt = 0; nt < 8; ++nt) {
            int o = nt * 16 + l16;
            float bias = bv[h * D_ + o];
            #pragma unroll
            for (int mt = 0; mt < 2; ++mt)
                #pragma unroll
                for (int r = 0; r < 4; ++r) {
                    int row = w * 32 + mt * 16 + quad * 4 + r;
                    Tv[o * TS + row] = f2h_bits(acc[mt][nt][r] + bias);
                }
        }
    }
    __syncthreads();

    // coalesced b128 stores, applying the attn pre-swizzle
    #pragma unroll
    for (int i = 0; i < 8; ++i) {
        int idx = tid + i * 256;
        int row = idx >> 4, c8 = (idx & 15) * 8;
        // K: global position c8 holds LOGICAL chunk (c8 ^ ((row&7)<<3))
        int lk = c8 ^ ((row & 7) << 3);
        uint4 dk = *(uint4*)&Tk[row * TS + (lk ^ (((row >> 2) & 3) << 3))];
        int m = m0 + row, bi = m >> 11, s = m & (S_ - 1);
        *(uint4*)&ko[(((size_t)bi * H_ + h) * S_ + s) * D_ + c8] = dk;
        // V: position c8 holds logical s-chunk (c8 ^ ((d&7)<<3)), d = row
        uint4 dv = *(uint4*)&Tv[row * TS + (c8 ^ ((row & 7) << 3))];
        int mg = m0 + c8, bv_i = mg >> 11, s0 = mg & (S_ - 1);
        *(uint4*)&vo[(((size_t)bv_i * H_ + h) * D_ + row) * S_ + s0] = dv;
    }
}

// ---------------- Flash attention ----------------
// grid: (S/128, H, B), block 256 (4 waves, 32 Q-rows each). BN = 64.
// LDS-throughput-bound fix: mt=2 means each kf/vf fragment read from LDS
// feeds TWO MFMAs -> per-CU LDS read volume halves vs 8-wave/16-row.
// LDS = K[2][64x128] + V[2][128x64] + P[128x64] = 81920 B -> 2 blocks/CU.
// 1 barrier/iter; K,V double-buffered via global_load_lds DMA (prefetch j+1
// issued at top of iter j, drained by the end-of-iter barrier).
// Q-scratch aliases Pbuf (waves 0,1) / Kbuf[1] (waves 2,3) so K0/V0 DMA
// overlaps the whole Q projection; single prologue barrier.
__global__ __launch_bounds__(256) void attn(
    const float* __restrict__ seq, const float* __restrict__ Wq,
    const float* __restrict__ bq,
    const ushort* __restrict__ kg, const ushort* __restrict__ vtg,
    float* __restrict__ out)
{
    constexpr int NT = S_ / 64;                      // 32 K/V tiles
    __shared__ alignas(16) ushort Kbuf[2][64 * 128]; // 32 KB
    __shared__ alignas(16) ushort Vbuf[2][128 * 64]; // 32 KB
    __shared__ alignas(16) ushort Pbuf[128 * 64];    // 16 KB, P^T[q][s]

    const int m0 = blockIdx.x * 128;
    const int h = blockIdx.y, bi = blockIdx.z;
    const int bh = bi * H_ + h;
    const int tid = threadIdx.x, lane = tid & 63, w = tid >> 6;
    const int l16 = lane & 15, quad = lane >> 4;
    const int swz = l16 & 7;
    const ushort* kbase = kg + (size_t)bh * S_ * D_;   // 64-row tile = 16 KB contiguous
    const ushort* vbase = vtg + (size_t)bh * D_ * S_;  // row stride S_
    const float qscale = 0.35355339059327373f * 1.4426950408889634f; // 1/sqrt(8)*log2e

    // ---- prologue: DMA K0 + V0 (overlaps Q projection below) ----
    #pragma unroll
    for (int c = 0; c < 4; ++c) {
        int i = w * 4 + c;
        gll16(kbase + i * 512 + lane * 8, &Kbuf[0][0] + i * 512);
        gll16(vbase + (size_t)(i * 8 + (lane >> 3)) * S_ + (lane & 7) * 8,
              &Vbuf[0][0] + i * 512);
    }

    // ---- Phase 0: Q tile = X Wq^T + bq (scaled) ----
    // scratch: waves 0,1 -> Pbuf (rows 0..63); waves 2,3 -> Kbuf[1] (rows 64..127)
    ushort* const Qs = (w < 2) ? &Pbuf[0] : &Kbuf[1][0];
    const int qlr = (w & 1) * 32;                    // local row base within scratch
    {
        f16x8 xa[2][4];
        #pragma unroll
        for (int mt = 0; mt < 2; ++mt)
            #pragma unroll
            for (int ks = 0; ks < 4; ++ks)
                xa[mt][ks] = pack8(&seq[((size_t)bi * S_ + m0 + w * 32 + mt * 16 + l16) * E_
                                        + h * D_ + ks * 32 + quad * 8]);
        f32x4 qacc[2][8];
        #pragma unroll
        for (int mt = 0; mt < 2; ++mt)
            #pragma unroll
            for (int nt = 0; nt < 8; ++nt) { f32x4 z = {0.f,0.f,0.f,0.f}; qacc[mt][nt] = z; }
        const float* W = Wq + (size_t)h * D_ * D_;
        #pragma unroll
        for (int ks = 0; ks < 4; ++ks)
            #pragma unroll
            for (int nt = 0; nt < 8; ++nt) {
                f16x8 bfr = pack8(&W[(size_t)(nt * 16 + l16) * D_ + ks * 32 + quad * 8]);
                #pragma unroll
                for (int mt = 0; mt < 2; ++mt)
                    qacc[mt][nt] = __builtin_amdgcn_mfma_f32_16x16x32_f16(
                        xa[mt][ks], bfr, qacc[mt][nt], 0, 0, 0);
            }
        #pragma unroll
        for (int nt = 0; nt < 8; ++nt) {
            int o = nt * 16 + l16;
            float bias = bq[h * D_ + o];
            #pragma unroll
            for (int mt = 0; mt < 2; ++mt)
                #pragma unroll
                for (int r = 0; r < 4; ++r) {
                    int row = qlr + mt * 16 + quad * 4 + r;
                    Qs[row * 128 + (o ^ (quad << 3))] =
                        f2h_bits((qacc[mt][nt][r] + bias) * qscale);
                }
        }
    }
    // qf[mt][ks]: Q[q=w*32+mt*16+l16][d=ks*32+quad*8..+7] (wave-private rows)
    f16x8 qf[2][4];
    #pragma unroll
    for (int mt = 0; mt < 2; ++mt)
        #pragma unroll
        for (int ks = 0; ks < 4; ++ks)
            qf[mt][ks] = *(const f16x8*)&Qs[(qlr + mt * 16 + l16) * 128
                                            + ks * 32 + ((quad ^ (l16 >> 2)) << 3)];

    f32x4 o_acc[2][8];    // O^T: d = nt*16+quad*4+r, q = w*32+mt*16+l16
    #pragma unroll
    for (int mt = 0; mt < 2; ++mt)
        #pragma unroll
        for (int nt = 0; nt < 8; ++nt) { f32x4 z = {0.f,0.f,0.f,0.f}; o_acc[mt][nt] = z; }
    float m_prev[2] = {-1e30f, -1e30f};
    float l_lane[2] = {0.f, 0.f};

    __syncthreads();   // qf in regs (lgkmcnt) + K0/V0 DMA drained (vmcnt)

    for (int j = 0; j < NT; ++j) {
        const int cur = j & 1;
        const ushort* KL = &Kbuf[cur][0];
        const ushort* VL = &Vbuf[cur][0];

        // prefetch tile j+1 (drains at this iter's end barrier)
        if (j + 1 < NT) {
            const ushort* kt = kbase + (size_t)(j + 1) * 64 * 128;
            const ushort* vt = vbase + (j + 1) * 64;
            ushort* kd = &Kbuf[cur ^ 1][0];
            ushort* vd = &Vbuf[cur ^ 1][0];
            #pragma unroll
            for (int c = 0; c < 4; ++c) {
                int i = w * 4 + c;
                gll16(kt + i * 512 + lane * 8, kd + i * 512);
                gll16(vt + (size_t)(i * 8 + (lane >> 3)) * S_ + (lane & 7) * 8,
                      vd + i * 512);
            }
        }

        // S^T = K Q^T: sacc[mt][nt]: s = nt*16+quad*4+r, q = w*32+mt*16+l16
        f32x4 sacc[2][4];
        #pragma unroll
        for (int mt = 0; mt < 2; ++mt)
            #pragma unroll
            for (int nt = 0; nt < 4; ++nt) { f32x4 z = {0.f,0.f,0.f,0.f}; sacc[mt][nt] = z; }
        __builtin_amdgcn_s_setprio(1);
        #pragma unroll
        for (int ks = 0; ks < 4; ++ks)
            #pragma unroll
            for (int nt = 0; nt < 4; ++nt) {
                f16x8 kf = *(const f16x8*)&KL[(nt * 16 + l16) * 128
                                              + (((ks * 4 + quad) ^ swz) << 3)];
                #pragma unroll
                for (int mt = 0; mt < 2; ++mt)
                    sacc[mt][nt] = __builtin_amdgcn_mfma_f32_16x16x32_f16(
                        kf, qf[mt][ks], sacc[mt][nt], 0, 0, 0);
            }
        __builtin_amdgcn_s_setprio(0);

        // online softmax — 16 lane-local s-values per mt
        uint2 pkw[2][4];
        #pragma unroll
        for (int mt = 0; mt < 2; ++mt) {
            float mx = fmaxf(fmaxf(sacc[mt][0][0], sacc[mt][0][1]),
                             fmaxf(sacc[mt][0][2], sacc[mt][0][3]));
            #pragma unroll
            for (int nt = 1; nt < 4; ++nt)
                mx = fmaxf(mx, fmaxf(fmaxf(sacc[mt][nt][0], sacc[mt][nt][1]),
                                     fmaxf(sacc[mt][nt][2], sacc[mt][nt][3])));
            mx = fmaxf(mx, __shfl_xor(mx, 16));
            mx = fmaxf(mx, __shfl_xor(mx, 32));
            // defer-max: rescale only when max grew past THR=8 (log2 domain, P<=256)
            if (__any(mx > m_prev[mt] + 8.0f)) {
                float mnew  = fmaxf(m_prev[mt], mx);
                float alpha = exp2f(m_prev[mt] - mnew);
                #pragma unroll
                for (int nt = 0; nt < 8; ++nt)
                    #pragma unroll
                    for (int r = 0; r < 4; ++r) o_acc[mt][nt][r] *= alpha;
                l_lane[mt] *= alpha;
                m_prev[mt] = mnew;
            }
            #pragma unroll
            for (int nt = 0; nt < 4; ++nt) {
                float e0 = exp2f(sacc[mt][nt][0] - m_prev[mt]);
                float e1 = exp2f(sacc[mt][nt][1] - m_prev[mt]);
                float e2 = exp2f(sacc[mt][nt][2] - m_prev[mt]);
                float e3 = exp2f(sacc[mt][nt][3] - m_prev[mt]);
                auto p01 = __builtin_amdgcn_cvt_pkrtz(e0, e1);
                auto p23 = __builtin_amdgcn_cvt_pkrtz(e2, e3);
                // denominator sees the same f16 quantization as the numerator
                l_lane[mt] += (float)p01[0] + (float)p01[1]
                            + (float)p23[0] + (float)p23[1];
                pkw[mt][nt] = make_uint2(__builtin_bit_cast(uint, p01),
                                         __builtin_bit_cast(uint, p23));
            }
        }

        // P^T[q][s] writes: b64 at 16B-group (2nt+(quad>>1))^swz, half quad&1
        #pragma unroll
        for (int mt = 0; mt < 2; ++mt) {
            ushort* prow = &Pbuf[(w * 32 + mt * 16 + l16) * 64];
            #pragma unroll
            for (int nt = 0; nt < 4; ++nt) {
                int G = 2 * nt + (quad >> 1);
                *(uint2*)&prow[((G ^ swz) << 3) + ((quad & 1) << 2)] = pkw[mt][nt];
            }
        }

        // O^T += V^T P^T  (A = Vt frag, B = own-row P^T frag)
        __builtin_amdgcn_s_setprio(1);
        #pragma unroll
        for (int ks = 0; ks < 2; ++ks) {
            f16x8 pb[2];
            #pragma unroll
            for (int mt = 0; mt < 2; ++mt)
                pb[mt] = *(const f16x8*)&Pbuf[(w * 32 + mt * 16 + l16) * 64
                                              + (((ks * 4 + quad) ^ swz) << 3)];
            #pragma unroll
            for (int nt = 0; nt < 8; ++nt) {
                f16x8 vf = *(const f16x8*)&VL[(nt * 16 + l16) * 64
                                              + (((ks * 4 + quad) ^ swz) << 3)];
                #pragma unroll
                for (int mt = 0; mt < 2; ++mt)
                    o_acc[mt][nt] = __builtin_amdgcn_mfma_f32_16x16x32_f16(
                        vf, pb[mt], o_acc[mt][nt], 0, 0, 0);
            }
        }
        __builtin_amdgcn_s_setprio(0);

        __syncthreads();   // reads of tile j done; tile j+1 DMA drained
    }

    // epilogue: complete l across quads, O/l, float4 stores to fp32 [B,S,E]
    #pragma unroll
    for (int mt = 0; mt < 2; ++mt) {
        float l = l_lane[mt];
        l += __shfl_xor(l, 16);
        l += __shfl_xor(l, 32);
        float rinv = 1.0f / l;
        const int q = m0 + w * 32 + mt * 16 + l16;
        #pragma unroll
        for (int nt = 0; nt < 8; ++nt) {
            float4 o;
            o.x = o_acc[mt][nt][0] * rinv;
            o.y = o_acc[mt][nt][1] * rinv;
            o.z = o_acc[mt][nt][2] * rinv;
            o.w = o_acc[mt][nt][3] * rinv;
            *(float4*)&out[((size_t)bi * S_ + q) * E_ + h * D_ + nt * 16 + quad * 4] = o;
        }
    }
}

extern "C" void kernel_launch(void* const* d_in, const int* in_sizes, int n_in,
                              void* d_out, int out_size, void* d_ws, size_t ws_size,
                              hipStream_t stream) {
    const float* seq = (const float*)d_in[0];
    const float* Wq  = (const float*)d_in[1];
    const float* Wk  = (const float*)d_in[2];
    const float* Wv  = (const float*)d_in[3];
    const float* bq  = (const float*)d_in[4];
    const float* bk  = (const float*)d_in[5];
    const float* bv  = (const float*)d_in[6];

    const size_t per = (size_t)B_ * H_ * S_ * D_;      // 8M elements
    if (ws_size < 2 * per * sizeof(ushort)) return;    // need 32 MB
    ushort* kws  = (ushort*)d_ws;          // [B,H,S,D]   pre-swizzled
    ushort* vtws = kws + per;              // [B,H,D,S]   pre-swizzled

    kv_proj<<<dim3(B_ * S_ / 128, H_), 256, 0, stream>>>(
        seq, Wk, Wv, bk, bv, kws, vtws);
    attn<<<dim3(S_ / 128, H_, B_), 256, 0, stream>>>(
        seq, Wq, bq, kws, vtws, (float*)d_out);
}